// Round 5
// baseline (429.097 us; speedup 1.0000x reference)
//
#include <hip/hip_runtime.h>
#include <hip/hip_bf16.h>
#include <stdint.h>

// SimLinear: C[50,8192] = x[50,8192] @ W[8192,8192]^T + bias
// R5: contiguity is the variable (64B->0.83, 1KB->1.3, 4KB->2.2 TB/s; staging
// mechanism proved irrelevant in R4). Each WG reads ONE contiguous 128 KB
// block (4 consecutive W rows) in address order; 8 waves sweep one 16 KB
// half-row each. W converted to bf16 during staging -> full 4x8192 bf16 tile
// in LDS (65.7 KB, 2 WGs/CU), K-loop has zero pack VALU (A = raw ds_read_b128,
// B = raw bf16x8 from packed x in L2). Full K per WG -> direct store, no atomics.

#define K_DIM  8192
#define O_DIM  8192
#define BATCH  50
#define BPAD   64
#define ROWS   4                    // consecutive W rows per WG -> 128 KB contiguous
#define NWG    (O_DIM / ROWS)       // 2048 WGs, 512 threads, 2 per CU
#define RSD    4104                 // LDS row stride in dwords (4096 + 8: 16B-aligned, conflict-free A reads)
#define XP_ELEMS ((size_t)(K_DIM / 8) * BPAD * 8)   // 1 MiB of bf16

typedef __attribute__((ext_vector_type(8)))  __bf16 bf16x8;
typedef __attribute__((ext_vector_type(4)))  float  f32x4;
typedef __attribute__((ext_vector_type(4)))  int    i32x4;

// fp32 pair -> dword of two bf16 (round-half-up): +0x8000 then high halves.
__device__ __forceinline__ unsigned bfpair(float a, float b) {
    unsigned ua = __float_as_uint(a) + 0x8000u;
    unsigned ub = __float_as_uint(b) + 0x8000u;
    return __builtin_amdgcn_perm(ub, ua, 0x07060302u);  // [a.hi16, b.hi16]
}

__device__ __forceinline__ bf16x8 pack8(float4 lo, float4 hi) {
    i32x4 p;
    p.x = (int)bfpair(lo.x, lo.y);
    p.y = (int)bfpair(lo.z, lo.w);
    p.z = (int)bfpair(hi.x, hi.y);
    p.w = (int)bfpair(hi.z, hi.w);
    return __builtin_bit_cast(bf16x8, p);
}

// Pack x[50,8192] fp32 -> XP[k/8][b(64)][8] bf16 (B-fragment octets, b>=50 = 0).
__global__ void pack_x(const float* __restrict__ X,
                       __hip_bfloat16* __restrict__ XP) {
    int i  = blockIdx.x * 256 + threadIdx.x;     // [0, 65536)
    int b  = i & 63;
    int ko = i >> 6;
    float4 z = {0.f, 0.f, 0.f, 0.f};
    float4 lo = z, hi = z;
    if (b < BATCH) {
        const float* xp = X + (size_t)b * K_DIM + (size_t)ko * 8;
        lo = *(const float4*)xp;
        hi = *(const float4*)(xp + 4);
    }
    *(bf16x8*)(XP + (size_t)i * 8) = pack8(lo, hi);
}

// WG: 4 consecutive W rows (one contiguous 128 KB block), full K.
// Stage: wave w sweeps half-row (row w>>1, half w&1): 16 KB sequential,
//   2 batches of 8 float4 loads -> pack -> ds_write_b64 (bf16).
// Compute: wave w owns k-chunk [w*1024, w*1024+1024): 32 steps of MFMA
//   16x16x32 bf16. A: one ds_read_b128 (lane m reads LDS row m&3 -> rows 4..15
//   duplicate rows 0..3; their C rows are garbage and never stored).
//   B: raw bf16x8 from XP (L2-resident). C/D: col=lane&15, row=(lane>>4)*4+reg.
// Epilogue: 8-wave k-reduce in LDS (valid rows = q==0, reg 0..3), store + bias.
template<bool PACKED>
__global__ __launch_bounds__(512, 4) void simlinear_mfma(
        const float* __restrict__ X,
        const float* __restrict__ W,
        const __hip_bfloat16* __restrict__ XP,
        const float* __restrict__ bias,
        float* __restrict__ out) {
    __shared__ int ldsd[ROWS * RSD];             // 4*4104 dw = 65,664 B

    const int tid   = threadIdx.x;
    const int wave  = tid >> 6;                  // 0..7
    const int lane  = tid & 63;
    const int l15   = lane & 15;
    const int q     = lane >> 4;                 // k-octet within step
    const int obase = blockIdx.x * ROWS;

    // ---- stage: contiguous sweep. wave w -> row w>>1, half w&1 (16 KB) ----
    {
        const int r = wave >> 1, h = wave & 1;
        const float* wbase = W + (size_t)(obase + r) * K_DIM + h * 4096 + lane * 4;
        const int    loff  = r * RSD + h * 2048 + lane * 2;
        float4 st[8];
        #pragma unroll
        for (int half = 0; half < 2; ++half) {
            #pragma unroll
            for (int c = 0; c < 8; ++c)
                st[c] = *(const float4*)(wbase + (half * 8 + c) * 256);
            #pragma unroll
            for (int c = 0; c < 8; ++c) {
                int2 p;
                p.x = (int)bfpair(st[c].x, st[c].y);
                p.y = (int)bfpair(st[c].z, st[c].w);
                *(int2*)&ldsd[loff + (half * 8 + c) * 128] = p;  // ds_write_b64
            }
        }
    }
    __syncthreads();

    // ---- compute: wave w -> k in [w*1024, w*1024+1024), 32 steps ----
    f32x4 acc[4] = {};                           // 4 b-groups x 4 f32 (C rows 0..3 valid)
    const int m    = l15 & 3;                    // LDS row (lanes 4..15 duplicate)
    const int abas = m * RSD + wave * 512 + q * 4;
    const int kob  = wave * 128 + q;             // global k-octet base

    #pragma unroll 4
    for (int S = 0; S < 32; ++S) {
        bf16x8 af = *(const bf16x8*)&ldsd[abas + S * 16];   // A[m][S*32+q*8 ..+8]
        const int ko = kob + S * 4;
        #pragma unroll
        for (int g = 0; g < 4; ++g) {
            bf16x8 bf;
            if (PACKED) {
                bf = *(const bf16x8*)(XP + ((size_t)ko * BPAD + g * 16 + l15) * 8);
            } else {
                const int b = g * 16 + l15;
                float4 z = {0.f, 0.f, 0.f, 0.f}, x0 = z, x1 = z;
                if (b < BATCH) {
                    const float* xp = X + (size_t)b * K_DIM + (size_t)ko * 8;
                    x0 = *(const float4*)xp;
                    x1 = *(const float4*)(xp + 4);
                }
                bf = pack8(x0, x1);
            }
            acc[g] = __builtin_amdgcn_mfma_f32_16x16x32_bf16(af, bf, acc[g], 0, 0, 0);
        }
    }
    __syncthreads();                             // all LDS reads done; reuse for reduce

    // ---- 8-wave k-reduce: red[w][b*4 + o], valid lanes q==0, regs 0..3 ----
    float* red = (float*)ldsd;
    if (q == 0) {
        #pragma unroll
        for (int g = 0; g < 4; ++g)
            #pragma unroll
            for (int r = 0; r < 4; ++r)
                red[wave * 256 + (g * 16 + l15) * 4 + r] = acc[g][r];
    }
    __syncthreads();

    if (tid < 256) {
        const int b = tid >> 2;                  // 0..63
        const int o = tid & 3;
        if (b < BATCH) {
            float s = bias[obase + o];
            #pragma unroll
            for (int w = 0; w < 8; ++w) s += red[w * 256 + tid];
            out[(size_t)b * O_DIM + obase + o] = s;
        }
    }
}

extern "C" void kernel_launch(void* const* d_in, const int* in_sizes, int n_in,
                              void* d_out, int out_size, void* d_ws, size_t ws_size,
                              hipStream_t stream) {
    const float* x    = (const float*)d_in[0];
    const float* w    = (const float*)d_in[1];
    const float* bias = (const float*)d_in[2];
    float* out = (float*)d_out;
    __hip_bfloat16* xp = (__hip_bfloat16*)d_ws;

    const bool packed = ws_size >= XP_ELEMS * sizeof(__hip_bfloat16);
    if (packed) {
        pack_x<<<(K_DIM / 8) * BPAD / 256, 256, 0, stream>>>(x, xp);
        simlinear_mfma<true><<<NWG, 512, 0, stream>>>(x, w, xp, bias, out);
    } else {
        simlinear_mfma<false><<<NWG, 512, 0, stream>>>(x, w, xp, bias, out);
    }
}